// Round 2
// baseline (319.388 us; speedup 1.0000x reference)
//
#include <hip/hip_runtime.h>
#include <math.h>
#include <stdint.h>

#define TOK 65536
#define DIN 256
#define EDIM 512
#define KCB 2048
#define NTB 128         // B n-tiles (2048/16)

// workspace layout (float offsets), 64-float aligned
#define OFF_MP   0u                     // M' fp32 [2048*256]
#define OFF_CP   524288u                // c' [2048]
#define OFF_Q    526336u                // Q [2048*256]
#define OFF_W2T  1050624u               // W2T [512*256]
#define OFF_U    1181696u               // u [512]
#define OFF_CQ   1182208u               // cQ [256]
#define OFF_BH   1182464u               // B packed bf16 [8][128][512]
#define TOT_F    1444608u

typedef short short8 __attribute__((ext_vector_type(8)));
typedef float f32x4 __attribute__((ext_vector_type(4)));

__device__ __forceinline__ unsigned short bf16rne(float x) {
    uint32_t u = __float_as_uint(x);
    u += 0x7fffu + ((u >> 16) & 1u);
    return (unsigned short)(u >> 16);
}
__device__ __forceinline__ void async_load16(const void* g, void* l) {
    __builtin_amdgcn_global_load_lds((const __attribute__((address_space(1))) void*)g,
                                     (__attribute__((address_space(3))) void*)l, 16, 0, 0);
}

// fused: zero loss scalar + usage bins, then W2T / u / cQ.
// blocks 0..511: e -> W2T[e][o], u[e];  512..767: o -> cQ[o]
__global__ void prep1_kernel(const float* __restrict__ W1, const float* __restrict__ W2,
                             const float* __restrict__ bn1_beta, const float* __restrict__ bn2_gamma,
                             const float* __restrict__ bn2_beta, const float* __restrict__ b2,
                             float* __restrict__ W2T, float* __restrict__ u, float* __restrict__ cQ,
                             float* __restrict__ out) {
    __shared__ float red[256];
    const int b = blockIdx.x, t = threadIdx.x;
    const int gid = b * 256 + t;
    if (gid == 0) out[0] = 0.0f;
    if (gid < KCB) out[1 + TOK * DIN + gid] = 0.0f;
    const float s = 1.0f / sqrtf(1.0f + 1e-5f);
    if (b < EDIM) {
        int e = b;
        W2T[e * DIN + t] = bn2_gamma[e] * s * W2[t * EDIM + e];
        float v = bn1_beta[t] * W1[e * DIN + t];
        red[t] = v; __syncthreads();
        for (int off = 128; off; off >>= 1) { if (t < off) red[t] += red[t + off]; __syncthreads(); }
        if (t == 0) u[e] = red[0];
    } else {
        int o = b - EDIM;
        float v = bn2_beta[t] * W2[o * EDIM + t] + bn2_beta[t + 256] * W2[o * EDIM + t + 256];
        red[t] = v; __syncthreads();
        for (int off = 128; off; off >>= 1) { if (t < off) red[t] += red[t + off]; __syncthreads(); }
        if (t == 0) cQ[o] = b2[o] + red[0];
    }
}

// per block: 4 codebook rows -> Mp, Q, AND c' (prep3 fused; E already in LDS).
__global__ __launch_bounds__(256) void prep2_kernel(const float* __restrict__ E, const float* __restrict__ W1,
                                                    const float* __restrict__ W2T, const float* __restrict__ bn1_gamma,
                                                    const float* __restrict__ cQ, const float* __restrict__ b1,
                                                    const float* __restrict__ u,
                                                    float* __restrict__ Mp, float* __restrict__ Q,
                                                    float* __restrict__ cp) {
    __shared__ float Elds[4 * EDIM]; // [r][e] row-major, 8 KB
    const int k0 = blockIdx.x * 4, t = threadIdx.x;
    const float4* src = (const float4*)(E + (size_t)k0 * EDIM);
    float4* dst = (float4*)Elds;
    dst[t] = src[t];
    dst[256 + t] = src[256 + t];
    __syncthreads();
    float m[4] = {0, 0, 0, 0};
    float q[4] = {0, 0, 0, 0};
    for (int e0 = 0; e0 < EDIM; e0 += 8) {
        float w1v[8], w2v[8];
#pragma unroll
        for (int j = 0; j < 8; j++) {
            w1v[j] = W1[(e0 + j) * DIN + t];
            w2v[j] = W2T[(e0 + j) * DIN + t];
        }
#pragma unroll
        for (int j = 0; j < 8; j++) {
#pragma unroll
            for (int r = 0; r < 4; r++) {
                float ev = Elds[r * EDIM + e0 + j];   // same-address broadcast
                m[r] += ev * w1v[j]; q[r] += ev * w2v[j];
            }
        }
    }
    const float s = 1.0f / sqrtf(1.0f + 1e-5f);
    const float gs = bn1_gamma[t] * s;
    const float cq = cQ[t];
#pragma unroll
    for (int r = 0; r < 4; r++) {
        Mp[(size_t)(k0 + r) * DIN + t] = gs * m[r];
        Q[(size_t)(k0 + r) * DIN + t] = q[r] + cq;
    }
    // fused prep3: c'[k0+r] = E[k]·(b1+u) - 0.5*||E[k]||², one wave per row
    const int r = t >> 6, l = t & 63;
    float sa = 0.0f, sb = 0.0f;
#pragma unroll
    for (int i = 0; i < 8; i++) {
        int e = l + i * 64;
        float ev = Elds[r * EDIM + e];
        float be = b1[e] + u[e];
        sa += ev * be; sb += ev * ev;
    }
    float v = sa - 0.5f * sb;
#pragma unroll
    for (int off = 32; off; off >>= 1) v += __shfl_down(v, off, 64);
    if (l == 0) cp[k0 + r] = v;
}

// Mp[2048 x 256] fp32 -> bf16 fragment-tile order (B). 64 blocks x 32 rows.
__global__ __launch_bounds__(256) void packB_kernel(const float* __restrict__ Mp,
                                                    unsigned short* __restrict__ Bh) {
    __shared__ __align__(16) unsigned short Hs[32 * 264];
    const int t = threadIdx.x, lane = t & 63, w = t >> 6;
    const int r0 = blockIdx.x * 32;
    const float4* src = (const float4*)(Mp + (size_t)r0 * DIN);
#pragma unroll
    for (int i = 0; i < 8; i++) {
        int id = i * 256 + t;
        int row = id >> 6, c4 = id & 63;
        float4 v = src[id];
        float f[4] = {v.x, v.y, v.z, v.w};
        ushort4 H;
        unsigned short* hp = (unsigned short*)&H;
#pragma unroll
        for (int j = 0; j < 4; j++) hp[j] = bf16rne(f[j]);
        *(ushort4*)&Hs[row * 264 + c4 * 4] = H;
    }
    __syncthreads();
#pragma unroll
    for (int q = 0; q < 4; q++) {
        int fb = q * 4 + w;
        int tl = fb >> 3, kc = fb & 7;
        int srow = tl * 16 + (lane & 15);
        int scol = kc * 32 + (lane >> 4) * 8;
        short8 vh = *(const short8*)&Hs[srow * 264 + scol];
        size_t off = ((size_t)kc * NTB + (r0 >> 4) + tl) * 512 + lane * 8;
        *(short8*)&Bh[off] = vh;
    }
}

// MEGA-KERNEL: A-stationary MFMA scorer + fused A-conversion + fused gather/
// loss/usage/output. Block = 128 rows x ALL 2048 codes.
// R2: 512 threads = 8 waves x 16 rows (was 4 waves x 32). Same grid (512
// blocks = 2/CU), same 2x32KB double-buffer + 32-stage structure as the
// proven R0 kernel -> 4 waves/SIMD instead of 2 for latency hiding.
__global__ __launch_bounds__(512) void score_fused_kernel(const float* __restrict__ flat,
                                                          const unsigned short* __restrict__ Bh,
                                                          const float* __restrict__ cp,
                                                          const float* __restrict__ Q,
                                                          float* __restrict__ out) {
    __shared__ __align__(16) unsigned short Blds[2][32 * 512];  // 64 KB
    __shared__ float cpl[KCB];                                  // 8 KB
    __shared__ int ksel[128];
    const int t = threadIdx.x, lane = t & 63, w = t >> 6;       // w = 0..7
    const int m0 = blockIdx.x * 128;
    const int fr = lane & 15, qr = lane >> 4;

    // A fragments from raw fp32 (one-time): af[kc], lane holds
    // row = w*16 + fr, cols kc*32 + qr*8 .. +8
    short8 af[8];
#pragma unroll
    for (int kc = 0; kc < 8; kc++) {
        int row = m0 + w * 16 + fr;
        const float* p = flat + (size_t)row * DIN + kc * 32 + qr * 8;
        float4 a = *(const float4*)p;
        float4 b = *(const float4*)(p + 4);
        float f[8] = {a.x, a.y, a.z, a.w, b.x, b.y, b.z, b.w};
        unsigned short* hp = (unsigned short*)&af[kc];
#pragma unroll
        for (int j = 0; j < 8; j++) hp[j] = bf16rne(f[j]);
    }

    // stage cp into LDS (512 threads x float4 = 2048)
    ((float4*)cpl)[t] = ((const float4*)cp)[t];

    // prefetch stage 0: 32 tiles (kc*4+nt); wave w stages tiles i*8+w, i=0..3
#pragma unroll
    for (int i = 0; i < 4; i++) {
        int tl = i * 8 + w;
        int kc = tl >> 2, nt = tl & 3;
        async_load16(Bh + ((size_t)kc * NTB + nt) * 512 + lane * 8,
                     &Blds[0][tl * 512 + lane * 8]);
    }
    __syncthreads();

    float bestv[4];
    int besti[4];
#pragma unroll
    for (int r = 0; r < 4; r++) { bestv[r] = -3.4e38f; besti[r] = 0; }

    const f32x4 ZERO4 = {0.f, 0.f, 0.f, 0.f};

#pragma unroll 1
    for (int s = 0; s < 32; s++) {
        const int cur = s & 1;
        if (s < 31) {
            const int nxt = cur ^ 1;
#pragma unroll
            for (int i = 0; i < 4; i++) {
                int tl = i * 8 + w;
                int kc = tl >> 2, nt = tl & 3;
                async_load16(Bh + ((size_t)kc * NTB + (s + 1) * 4 + nt) * 512 + lane * 8,
                             &Blds[nxt][tl * 512 + lane * 8]);
            }
        }
        f32x4 acc[4];
        __builtin_amdgcn_s_setprio(1);
        {   // kc = 0: C = 0 operand (no acc init pass)
            short8 bf[4];
#pragma unroll
            for (int nt = 0; nt < 4; nt++)
                bf[nt] = *(const short8*)&Blds[cur][nt * 512 + lane * 8];
#pragma unroll
            for (int nt = 0; nt < 4; nt++)
                acc[nt] = __builtin_amdgcn_mfma_f32_16x16x32_bf16(af[0], bf[nt], ZERO4, 0, 0, 0);
        }
#pragma unroll
        for (int kc = 1; kc < 8; kc++) {
            short8 bf[4];
#pragma unroll
            for (int nt = 0; nt < 4; nt++)
                bf[nt] = *(const short8*)&Blds[cur][(kc * 4 + nt) * 512 + lane * 8];
#pragma unroll
            for (int nt = 0; nt < 4; nt++)
                acc[nt] = __builtin_amdgcn_mfma_f32_16x16x32_bf16(af[kc], bf[nt], acc[nt], 0, 0, 0);
        }
        __builtin_amdgcn_s_setprio(0);

        // epilogue: cols s*64 + nt*16 + fr (cp from LDS)
        const int base = s * 64 + fr;
        float cpv[4];
        int cidx[4];
#pragma unroll
        for (int nt = 0; nt < 4; nt++) { cpv[nt] = cpl[base + nt * 16]; cidx[nt] = base + nt * 16; }
#pragma unroll
        for (int r = 0; r < 4; r++) {
            float v = acc[0][r] + cpv[0];
            int ci = cidx[0];
#pragma unroll
            for (int nt = 1; nt < 4; nt++) {
                float vi = acc[nt][r] + cpv[nt];
                if (vi > v) { v = vi; ci = cidx[nt]; }   // asc nt: ties -> lower
            }
            if (v > bestv[r]) { bestv[r] = v; besti[r] = ci; }  // asc s
        }
        __syncthreads();
    }

    // cross-fr argmax reduce (within 16-lane groups), tie -> lower idx
#pragma unroll
    for (int r = 0; r < 4; r++) {
        float bv = bestv[r];
        int bc = besti[r];
#pragma unroll
        for (int xm = 1; xm < 16; xm <<= 1) {
            float ov = __shfl_xor(bv, xm, 64);
            int oc = __shfl_xor(bc, xm, 64);
            if (ov > bv || (ov == bv && oc < bc)) { bv = ov; bc = oc; }
        }
        if (fr == 0) ksel[w * 16 + qr * 4 + r] = bc;
    }
    __syncthreads();

    // fused gather: wave w handles its own 16 rows
    float lsum = 0.0f;
    for (int rr = 0; rr < 16; rr++) {
        int rl = w * 16 + rr;
        int row = m0 + rl;
        int k = ksel[rl];                       // same-address broadcast
        const float* qr_ = Q + (size_t)k * DIN;
        const float* xr = flat + (size_t)row * DIN;
        float* ob = out + 1 + (size_t)row * DIN;
#pragma unroll
        for (int cc = 0; cc < 4; cc++) {
            int j = lane + 64 * cc;
            float q = qr_[j];
            float d = q - xr[j];
            lsum += d * d;
            ob[j] = q;
        }
        if (lane == 0) atomicAdd(out + 1 + TOK * DIN + k, 1.0f / (float)TOK);
    }
#pragma unroll
    for (int off = 32; off; off >>= 1) lsum += __shfl_down(lsum, off, 64);
    if (lane == 0) atomicAdd(out, lsum * (1.25f / (float)((size_t)TOK * DIN)));
}

extern "C" void kernel_launch(void* const* d_in, const int* in_sizes, int n_in,
                              void* d_out, int out_size, void* d_ws, size_t ws_size,
                              hipStream_t stream) {
    const float* inputs = (const float*)d_in[0];
    const float* bn1_gamma = (const float*)d_in[1];
    const float* bn1_beta  = (const float*)d_in[2];
    const float* W1 = (const float*)d_in[3];
    const float* b1 = (const float*)d_in[4];
    const float* E  = (const float*)d_in[5];
    const float* bn2_gamma = (const float*)d_in[6];
    const float* bn2_beta  = (const float*)d_in[7];
    const float* W2 = (const float*)d_in[8];
    const float* b2 = (const float*)d_in[9];

    float* ws = (float*)d_ws;
    float* Mp  = ws + OFF_MP;
    float* cp  = ws + OFF_CP;
    float* Q   = ws + OFF_Q;
    float* W2T = ws + OFF_W2T;
    float* u   = ws + OFF_U;
    float* cQ  = ws + OFF_CQ;
    unsigned short* Bh = (unsigned short*)(ws + OFF_BH);
    float* out = (float*)d_out;

    hipLaunchKernelGGL(prep1_kernel, dim3(768), dim3(256), 0, stream,
                       W1, W2, bn1_beta, bn2_gamma, bn2_beta, b2, W2T, u, cQ, out);
    hipLaunchKernelGGL(prep2_kernel, dim3(512), dim3(256), 0, stream,
                       E, W1, W2T, bn1_gamma, cQ, b1, u, Mp, Q, cp);
    hipLaunchKernelGGL(packB_kernel, dim3(64), dim3(256), 0, stream, Mp, Bh);
    hipLaunchKernelGGL(score_fused_kernel, dim3(512), dim3(512), 0, stream,
                       inputs, Bh, cp, Q, out);
}

// Round 3
// 264.143 us; speedup vs baseline: 1.2091x; 1.2091x over previous
//
#include <hip/hip_runtime.h>
#include <math.h>
#include <stdint.h>

#define TOK 65536
#define DIN 256
#define EDIM 512
#define KCB 2048
#define NTB 128         // B n-tiles (2048/16)

// workspace layout (float offsets), 64-float aligned
#define OFF_MP   0u                     // (unused after fusion; kept for layout stability)
#define OFF_CP   524288u                // c' [2048]
#define OFF_Q    526336u                // Q [2048*256]
#define OFF_W2T  1050624u               // W2T [512*256]
#define OFF_U    1181696u               // u [512]
#define OFF_CQ   1182208u               // cQ [256]
#define OFF_BH   1182464u               // B packed bf16 [8][128][512]
#define TOT_F    1444608u

typedef short short8 __attribute__((ext_vector_type(8)));
typedef float f32x4 __attribute__((ext_vector_type(4)));

__device__ __forceinline__ unsigned short bf16rne(float x) {
    uint32_t u = __float_as_uint(x);
    u += 0x7fffu + ((u >> 16) & 1u);
    return (unsigned short)(u >> 16);
}
__device__ __forceinline__ void async_load16(const void* g, void* l) {
    __builtin_amdgcn_global_load_lds((const __attribute__((address_space(1))) void*)g,
                                     (__attribute__((address_space(3))) void*)l, 16, 0, 0);
}

// fused: zero loss scalar + usage bins, then W2T / u / cQ.
// blocks 0..511: e -> W2T[e][o], u[e];  512..767: o -> cQ[o]
__global__ void prep1_kernel(const float* __restrict__ W1, const float* __restrict__ W2,
                             const float* __restrict__ bn1_beta, const float* __restrict__ bn2_gamma,
                             const float* __restrict__ bn2_beta, const float* __restrict__ b2,
                             float* __restrict__ W2T, float* __restrict__ u, float* __restrict__ cQ,
                             float* __restrict__ out) {
    __shared__ float red[256];
    const int b = blockIdx.x, t = threadIdx.x;
    const int gid = b * 256 + t;
    if (gid == 0) out[0] = 0.0f;
    if (gid < KCB) out[1 + TOK * DIN + gid] = 0.0f;
    const float s = 1.0f / sqrtf(1.0f + 1e-5f);
    if (b < EDIM) {
        int e = b;
        W2T[e * DIN + t] = bn2_gamma[e] * s * W2[t * EDIM + e];
        float v = bn1_beta[t] * W1[e * DIN + t];
        red[t] = v; __syncthreads();
        for (int off = 128; off; off >>= 1) { if (t < off) red[t] += red[t + off]; __syncthreads(); }
        if (t == 0) u[e] = red[0];
    } else {
        int o = b - EDIM;
        float v = bn2_beta[t] * W2[o * EDIM + t] + bn2_beta[t + 256] * W2[o * EDIM + t + 256];
        red[t] = v; __syncthreads();
        for (int off = 128; off; off >>= 1) { if (t < off) red[t] += red[t + off]; __syncthreads(); }
        if (t == 0) cQ[o] = b2[o] + red[0];
    }
}

// FUSED prep2+packB: 256 blocks x 512 threads; 8 codebook rows per block
// (half h = t>>8 owns rows h*4..h*4+3, col = t&255).
// Broadcast operand E read via wave-uniform SCALAR loads (SMEM path, no LDS
// pipe cost, no per-wave re-read). W1/W2T stream coalesced; the two halves
// read identical addresses -> L1 dedup (256 MB L2 traffic total vs 512 MB).
// Outputs: Q (fp32), cp, and Bh bf16 MFMA fragments DIRECTLY (Mp/packB gone).
// Per-accumulator summation order identical to the previous version -> bit-exact.
__global__ __launch_bounds__(512) void prep2_kernel(const float* __restrict__ E, const float* __restrict__ W1,
                                                    const float* __restrict__ W2T, const float* __restrict__ bn1_gamma,
                                                    const float* __restrict__ cQ, const float* __restrict__ b1,
                                                    const float* __restrict__ u,
                                                    float* __restrict__ Q, float* __restrict__ cp,
                                                    unsigned short* __restrict__ Bh) {
    __shared__ __align__(16) unsigned short hs[8][264];   // bf16 of Mp rows, padded
    const int t = threadIdx.x;
    const int col = t & 255;
    const int half = __builtin_amdgcn_readfirstlane(t >> 8);   // wave-uniform 0/1
    const int k0 = blockIdx.x * 8;
    const float* __restrict__ Ek = E + ((size_t)k0 + (size_t)half * 4) * EDIM;

    float m[4] = {0, 0, 0, 0};
    float q[4] = {0, 0, 0, 0};
    for (int e0 = 0; e0 < EDIM; e0 += 8) {
        float w1v[8], w2v[8];
#pragma unroll
        for (int j = 0; j < 8; j++) {
            w1v[j] = W1[(e0 + j) * DIN + col];
            w2v[j] = W2T[(e0 + j) * DIN + col];
        }
#pragma unroll
        for (int r = 0; r < 4; r++) {
#pragma unroll
            for (int j = 0; j < 8; j++) {
                float ev = Ek[(size_t)r * EDIM + e0 + j];   // uniform -> s_load
                m[r] += ev * w1v[j];
                q[r] += ev * w2v[j];
            }
        }
    }
    const float s = 1.0f / sqrtf(1.0f + 1e-5f);
    const float gs = bn1_gamma[col] * s;
    const float cq = cQ[col];
#pragma unroll
    for (int r = 0; r < 4; r++) {
        Q[(size_t)(k0 + half * 4 + r) * DIN + col] = q[r] + cq;
        hs[half * 4 + r][col] = bf16rne(gs * m[r]);
    }

    // fused prep3: c'[k0+wv] = E[k]·(b1+u) - 0.5*||E[k]||², one wave per row
    {
        const int wv = t >> 6, l = t & 63;
        const float* __restrict__ Er = E + (size_t)(k0 + wv) * EDIM;
        float sa = 0.0f, sb = 0.0f;
#pragma unroll
        for (int i = 0; i < 8; i++) {
            int e = l + i * 64;
            float ev = Er[e];
            float be = b1[e] + u[e];
            sa += ev * be; sb += ev * ev;
        }
        float v = sa - 0.5f * sb;
#pragma unroll
        for (int off = 32; off; off >>= 1) v += __shfl_down(v, off, 64);
        if (l == 0) cp[k0 + wv] = v;
    }

    __syncthreads();   // hs complete

    // Bh fragment write: 256 chunks of 16B (8 rows x 8 kc x 4 qr), threads t<256.
    // Tile (kc, nt=k0>>4): lane l2 holds code col (l2&15), K-cols kc*32+(l2>>4)*8.
    if (t < 256) {
        const int rr = t & 7, qr = (t >> 3) & 3, kc = t >> 5;
        const int nt = k0 >> 4;
        const int l2 = (k0 & 8) + rr + (qr << 4);
        short8 vh = *(const short8*)&hs[rr][kc * 32 + qr * 8];
        *(short8*)&Bh[((size_t)kc * NTB + nt) * 512 + (size_t)l2 * 8] = vh;
    }
}

// MEGA-KERNEL: A-stationary MFMA scorer + fused A-conversion + fused gather/
// loss/usage/output. Block = 128 rows x ALL 2048 codes, 4 waves x 32 rows.
// (proven R0 structure: 2x32KB dbuf, 32 stages, 64 MFMA/wave/stage)
__global__ __launch_bounds__(256) void score_fused_kernel(const float* __restrict__ flat,
                                                          const unsigned short* __restrict__ Bh,
                                                          const float* __restrict__ cp,
                                                          const float* __restrict__ Q,
                                                          float* __restrict__ out) {
    __shared__ __align__(16) unsigned short Blds[2][32 * 512];  // 64 KB
    __shared__ int ksel[128];
    const int t = threadIdx.x, lane = t & 63, w = t >> 6;
    const int m0 = blockIdx.x * 128;
    const int fr = lane & 15, qr = lane >> 4;

    // A fragments from raw fp32 (one-time): af[kc][mt], lane holds
    // row = w*32 + mt*16 + fr, cols kc*32 + qr*8 .. +8
    short8 af[8][2];
#pragma unroll
    for (int kc = 0; kc < 8; kc++)
#pragma unroll
        for (int mt = 0; mt < 2; mt++) {
            int row = m0 + w * 32 + mt * 16 + fr;
            const float* p = flat + (size_t)row * DIN + kc * 32 + qr * 8;
            float4 a = *(const float4*)p;
            float4 b = *(const float4*)(p + 4);
            float f[8] = {a.x, a.y, a.z, a.w, b.x, b.y, b.z, b.w};
            unsigned short* hp = (unsigned short*)&af[kc][mt];
#pragma unroll
            for (int j = 0; j < 8; j++) hp[j] = bf16rne(f[j]);
        }

    // prefetch stage 0: 32 tiles (kc*4+nt); thread stages tiles i*4+w, i=0..7
#pragma unroll
    for (int i = 0; i < 8; i++) {
        int tl = i * 4 + w;
        int kc = tl >> 2, nt = tl & 3;
        async_load16(Bh + ((size_t)kc * NTB + nt) * 512 + lane * 8,
                     &Blds[0][tl * 512 + lane * 8]);
    }
    __syncthreads();

    float bestv[2][4];
    int besti[2][4];
#pragma unroll
    for (int mt = 0; mt < 2; mt++)
#pragma unroll
        for (int r = 0; r < 4; r++) { bestv[mt][r] = -3.4e38f; besti[mt][r] = 0; }

    const f32x4 ZERO4 = {0.f, 0.f, 0.f, 0.f};

#pragma unroll 1
    for (int s = 0; s < 32; s++) {
        const int cur = s & 1;
        if (s < 31) {
            const int nxt = cur ^ 1;
#pragma unroll
            for (int i = 0; i < 8; i++) {
                int tl = i * 4 + w;
                int kc = tl >> 2, nt = tl & 3;
                async_load16(Bh + ((size_t)kc * NTB + (s + 1) * 4 + nt) * 512 + lane * 8,
                             &Blds[nxt][tl * 512 + lane * 8]);
            }
        }
        f32x4 acc[2][4];
        {   // kc = 0: C = 0 operand (no acc init pass)
            short8 bf[4];
#pragma unroll
            for (int nt = 0; nt < 4; nt++)
                bf[nt] = *(const short8*)&Blds[cur][nt * 512 + lane * 8];
#pragma unroll
            for (int mt = 0; mt < 2; mt++)
#pragma unroll
                for (int nt = 0; nt < 4; nt++)
                    acc[mt][nt] = __builtin_amdgcn_mfma_f32_16x16x32_bf16(af[0][mt], bf[nt], ZERO4, 0, 0, 0);
        }
#pragma unroll
        for (int kc = 1; kc < 8; kc++) {
            short8 bf[4];
#pragma unroll
            for (int nt = 0; nt < 4; nt++)
                bf[nt] = *(const short8*)&Blds[cur][(kc * 4 + nt) * 512 + lane * 8];
#pragma unroll
            for (int mt = 0; mt < 2; mt++)
#pragma unroll
                for (int nt = 0; nt < 4; nt++)
                    acc[mt][nt] = __builtin_amdgcn_mfma_f32_16x16x32_bf16(af[kc][mt], bf[nt], acc[mt][nt], 0, 0, 0);
        }
        // epilogue: cols s*64 + nt*16 + fr
        const int base = s * 64 + fr;
        float cpv[4];
        int cidx[4];
#pragma unroll
        for (int nt = 0; nt < 4; nt++) { cpv[nt] = cp[base + nt * 16]; cidx[nt] = base + nt * 16; }
#pragma unroll
        for (int mt = 0; mt < 2; mt++)
#pragma unroll
            for (int r = 0; r < 4; r++) {
                float v = acc[mt][0][r] + cpv[0];
                int ci = cidx[0];
#pragma unroll
                for (int nt = 1; nt < 4; nt++) {
                    float vi = acc[mt][nt][r] + cpv[nt];
                    if (vi > v) { v = vi; ci = cidx[nt]; }   // asc nt: ties -> lower
                }
                if (v > bestv[mt][r]) { bestv[mt][r] = v; besti[mt][r] = ci; }  // asc s
            }
        __syncthreads();
    }

    // cross-fr argmax reduce (within 16-lane groups), tie -> lower idx
#pragma unroll
    for (int mt = 0; mt < 2; mt++)
#pragma unroll
        for (int r = 0; r < 4; r++) {
            float bv = bestv[mt][r];
            int bc = besti[mt][r];
#pragma unroll
            for (int xm = 1; xm < 16; xm <<= 1) {
                float ov = __shfl_xor(bv, xm, 64);
                int oc = __shfl_xor(bc, xm, 64);
                if (ov > bv || (ov == bv && oc < bc)) { bv = ov; bc = oc; }
            }
            if (fr == 0) ksel[w * 32 + mt * 16 + qr * 4 + r] = bc;
        }
    __syncthreads();

    // fused gather: wave w handles its own 32 rows
    float lsum = 0.0f;
    for (int rr = 0; rr < 32; rr++) {
        int rl = w * 32 + rr;
        int row = m0 + rl;
        int k = ksel[rl];                       // same-address broadcast
        const float* qr_ = Q + (size_t)k * DIN;
        const float* xr = flat + (size_t)row * DIN;
        float* ob = out + 1 + (size_t)row * DIN;
#pragma unroll
        for (int cc = 0; cc < 4; cc++) {
            int j = lane + 64 * cc;
            float q = qr_[j];
            float d = q - xr[j];
            lsum += d * d;
            ob[j] = q;
        }
        if (lane == 0) atomicAdd(out + 1 + TOK * DIN + k, 1.0f / (float)TOK);
    }
#pragma unroll
    for (int off = 32; off; off >>= 1) lsum += __shfl_down(lsum, off, 64);
    if (lane == 0) atomicAdd(out, lsum * (1.25f / (float)((size_t)TOK * DIN)));
}

extern "C" void kernel_launch(void* const* d_in, const int* in_sizes, int n_in,
                              void* d_out, int out_size, void* d_ws, size_t ws_size,
                              hipStream_t stream) {
    const float* inputs = (const float*)d_in[0];
    const float* bn1_gamma = (const float*)d_in[1];
    const float* bn1_beta  = (const float*)d_in[2];
    const float* W1 = (const float*)d_in[3];
    const float* b1 = (const float*)d_in[4];
    const float* E  = (const float*)d_in[5];
    const float* bn2_gamma = (const float*)d_in[6];
    const float* bn2_beta  = (const float*)d_in[7];
    const float* W2 = (const float*)d_in[8];
    const float* b2 = (const float*)d_in[9];

    float* ws = (float*)d_ws;
    float* cp  = ws + OFF_CP;
    float* Q   = ws + OFF_Q;
    float* W2T = ws + OFF_W2T;
    float* u   = ws + OFF_U;
    float* cQ  = ws + OFF_CQ;
    unsigned short* Bh = (unsigned short*)(ws + OFF_BH);
    float* out = (float*)d_out;

    hipLaunchKernelGGL(prep1_kernel, dim3(768), dim3(256), 0, stream,
                       W1, W2, bn1_beta, bn2_gamma, bn2_beta, b2, W2T, u, cQ, out);
    hipLaunchKernelGGL(prep2_kernel, dim3(256), dim3(512), 0, stream,
                       E, W1, W2T, bn1_gamma, cQ, b1, u, Q, cp, Bh);
    hipLaunchKernelGGL(score_fused_kernel, dim3(512), dim3(256), 0, stream,
                       inputs, Bh, cp, Q, out);
}